// Round 7
// baseline (190.109 us; speedup 1.0000x reference)
//
#include <hip/hip_runtime.h>
#include <math.h>

#define B 128
#define H 2048
#define S 512
#define FOURH 8192
#define LOG2E 1.4426950408889634f

typedef float  f32x4  __attribute__((ext_vector_type(4)));
typedef short  bf16x8 __attribute__((ext_vector_type(8)));
typedef unsigned short u16;
typedef unsigned short u16x8 __attribute__((ext_vector_type(8)));
typedef unsigned short u16x4 __attribute__((ext_vector_type(4)));

// Split f32 -> bf16 hi + bf16 lo (truncation; lo captures residual, total ~2^-16)
__device__ __forceinline__ void cvt_hilo(float x, u16& h, u16& lo) {
    unsigned int u = __float_as_uint(x);
    h = (u16)(u >> 16);
    float hf = __uint_as_float(u & 0xFFFF0000u);
    float r = x - hf;
    lo = (u16)(__float_as_uint(r) >> 16);
}

// ---------------------------------------------------------------------------
// Kernel 1: build A0 = [embed[tw] | hx] as bf16 hi/lo pair [128][4096]
// ---------------------------------------------------------------------------
__global__ __launch_bounds__(256) void gather_convert_A0(
    const int* __restrict__ tw,
    const float* __restrict__ embed,
    const float* __restrict__ hx,
    u16* __restrict__ Ah, u16* __restrict__ Al)
{
    const int i = (blockIdx.x * 256 + threadIdx.x) * 8;   // over 128*4096
    const int b = i >> 12;
    const int col = i & 4095;
    const float* src = (col < H) ? (embed + (size_t)tw[b] * H + col)
                                 : (hx + (size_t)b * H + (col - H));
    f32x4 v0 = *(const f32x4*)(src);
    f32x4 v1 = *(const f32x4*)(src + 4);
    u16x8 hv, lv;
    #pragma unroll
    for (int j = 0; j < 4; ++j) { u16 h, l; cvt_hilo(v0[j], h, l); hv[j] = h; lv[j] = l; }
    #pragma unroll
    for (int j = 0; j < 4; ++j) { u16 h, l; cvt_hilo(v1[j], h, l); hv[4+j] = h; lv[4+j] = l; }
    *(u16x8*)(Ah + i) = hv;
    *(u16x8*)(Al + i) = lv;
}

// ---------------------------------------------------------------------------
// Split-bf16 MFMA GEMM for gates, 128x128 tile, split-K 8.
// BM=128, BN=128, BK=32, 256 threads = 4 waves (2x2), 4x4 frags/wave.
// kz<4 -> W_ih, else W_hh; col offset (kz&3)*512. out [8][128][8192].
// ---------------------------------------------------------------------------
__global__ __launch_bounds__(256) void gates_gemm(
    const u16* __restrict__ Ah, const u16* __restrict__ Al,
    const float* __restrict__ W0, const float* __restrict__ W1,
    float* __restrict__ outp)
{
    constexpr int KLEN = 512;
    constexpr int NITER = KLEN / 32;       // 16
    __shared__ u16 AhS[128][40];
    __shared__ u16 AlS[128][40];
    __shared__ u16 BhS[128][40];
    __shared__ u16 BlS[128][40];

    const int tid = threadIdx.x;
    const int n0 = blockIdx.x * 128;
    const int kz = blockIdx.y;
    const int kbase = kz * KLEN;
    const int sr = tid >> 1;
    const int sc = (tid & 1) * 16;
    const int wv = tid >> 6, lane = tid & 63;
    const int wr = (wv >> 1) * 64;
    const int wc = (wv & 1) * 64;
    const int frow = lane & 15, fk = (lane >> 4) * 8, crow = (lane >> 4) * 4;

    const float* Wrow = ((kz < 4) ? W0 : W1) + (size_t)(n0 + sr) * H + (kz & 3) * KLEN + sc;
    const u16* Abase = Ah + (size_t)sr * 4096 + kbase + sc;
    const u16* Lbase = Al + (size_t)sr * 4096 + kbase + sc;

    f32x4 acc[4][4];
    #pragma unroll
    for (int mi = 0; mi < 4; ++mi)
        #pragma unroll
        for (int ni = 0; ni < 4; ++ni)
            acc[mi][ni] = (f32x4){0.f, 0.f, 0.f, 0.f};

    u16x8 rah0, rah1, ral0, ral1;
    auto loadA = [&](int k0) {
        rah0 = *(const u16x8*)(Abase + k0);
        rah1 = *(const u16x8*)(Abase + k0 + 8);
        ral0 = *(const u16x8*)(Lbase + k0);
        ral1 = *(const u16x8*)(Lbase + k0 + 8);
    };
    auto writeA = [&]() {
        *(u16x8*)&AhS[sr][sc]     = rah0;
        *(u16x8*)&AhS[sr][sc + 8] = rah1;
        *(u16x8*)&AlS[sr][sc]     = ral0;
        *(u16x8*)&AlS[sr][sc + 8] = ral1;
    };
    f32x4 wX0, wX1, wX2, wX3, wY0, wY1, wY2, wY3;
    auto loadWX = [&](int k0) {
        wX0 = *(const f32x4*)(Wrow + k0);
        wX1 = *(const f32x4*)(Wrow + k0 + 4);
        wX2 = *(const f32x4*)(Wrow + k0 + 8);
        wX3 = *(const f32x4*)(Wrow + k0 + 12);
    };
    auto loadWY = [&](int k0) {
        wY0 = *(const f32x4*)(Wrow + k0);
        wY1 = *(const f32x4*)(Wrow + k0 + 4);
        wY2 = *(const f32x4*)(Wrow + k0 + 8);
        wY3 = *(const f32x4*)(Wrow + k0 + 12);
    };
    auto writeB = [&](const f32x4& b0, const f32x4& b1,
                      const f32x4& b2, const f32x4& b3) {
        u16x8 hv, lv;
        #pragma unroll
        for (int j = 0; j < 4; ++j) { u16 h, l; cvt_hilo(b0[j], h, l); hv[j] = h; lv[j] = l; }
        #pragma unroll
        for (int j = 0; j < 4; ++j) { u16 h, l; cvt_hilo(b1[j], h, l); hv[4+j] = h; lv[4+j] = l; }
        *(u16x8*)&BhS[sr][sc] = hv;
        *(u16x8*)&BlS[sr][sc] = lv;
        #pragma unroll
        for (int j = 0; j < 4; ++j) { u16 h, l; cvt_hilo(b2[j], h, l); hv[j] = h; lv[j] = l; }
        #pragma unroll
        for (int j = 0; j < 4; ++j) { u16 h, l; cvt_hilo(b3[j], h, l); hv[4+j] = h; lv[4+j] = l; }
        *(u16x8*)&BhS[sr][sc + 8] = hv;
        *(u16x8*)&BlS[sr][sc + 8] = lv;
    };
    auto computeTile = [&]() {
        bf16x8 a_h[4], a_l[4], b_h[4], b_l[4];
        #pragma unroll
        for (int mi = 0; mi < 4; ++mi) {
            a_h[mi] = *(const bf16x8*)&AhS[wr + mi * 16 + frow][fk];
            a_l[mi] = *(const bf16x8*)&AlS[wr + mi * 16 + frow][fk];
        }
        #pragma unroll
        for (int ni = 0; ni < 4; ++ni) {
            b_h[ni] = *(const bf16x8*)&BhS[wc + ni * 16 + frow][fk];
            b_l[ni] = *(const bf16x8*)&BlS[wc + ni * 16 + frow][fk];
        }
        #pragma unroll
        for (int mi = 0; mi < 4; ++mi)
            #pragma unroll
            for (int ni = 0; ni < 4; ++ni) {
                acc[mi][ni] = __builtin_amdgcn_mfma_f32_16x16x32_bf16(a_h[mi], b_h[ni], acc[mi][ni], 0, 0, 0);
                acc[mi][ni] = __builtin_amdgcn_mfma_f32_16x16x32_bf16(a_h[mi], b_l[ni], acc[mi][ni], 0, 0, 0);
                acc[mi][ni] = __builtin_amdgcn_mfma_f32_16x16x32_bf16(a_l[mi], b_h[ni], acc[mi][ni], 0, 0, 0);
            }
    };

    loadWX(0);
    loadWY(32);
    loadA(0);

    for (int ks = 0; ks < NITER; ks += 2) {
        __syncthreads();
        writeA();
        writeB(wX0, wX1, wX2, wX3);
        __syncthreads();
        loadA((ks + 1) * 32);
        if (ks + 2 < NITER) loadWX((ks + 2) * 32);
        computeTile();
        __syncthreads();
        writeA();
        writeB(wY0, wY1, wY2, wY3);
        __syncthreads();
        if (ks + 2 < NITER) loadA((ks + 2) * 32);
        if (ks + 3 < NITER) loadWY((ks + 3) * 32);
        computeTile();
    }

    #pragma unroll
    for (int mi = 0; mi < 4; ++mi)
        #pragma unroll
        for (int ni = 0; ni < 4; ++ni) {
            const int col = n0 + wc + ni * 16 + frow;
            #pragma unroll
            for (int j = 0; j < 4; ++j) {
                const int row = wr + mi * 16 + crow + j;
                outp[((size_t)kz * B + row) * FOURH + col] = acc[mi][ni][j];
            }
        }
}

// ---------------------------------------------------------------------------
// gemm1 tile body (device fn): 128x128 tile of out = A1 @ attn_W^T over a
// 256-wide K slice. Used by the merged attn kernel (hx half, K 2048..4095)
// and by the content-half kernel (K 0..2047). LDS passed in (manual union).
// ---------------------------------------------------------------------------
__device__ __forceinline__ void gemm1_tile(
    unsigned char* smem,
    const u16* __restrict__ Ah, const u16* __restrict__ Al,
    const float* __restrict__ attn_W,
    int n0, int kbase, int kzout, float* __restrict__ outp)
{
    constexpr int NITER = 8;   // 256 / 32
    typedef u16 (*tile_t)[40];
    tile_t AhS = (tile_t)(smem);
    tile_t AlS = (tile_t)(smem + 10240);
    tile_t BhS = (tile_t)(smem + 20480);
    tile_t BlS = (tile_t)(smem + 30720);

    const int tid = threadIdx.x;
    const int sr = tid >> 1;
    const int sc = (tid & 1) * 16;
    const int wv = tid >> 6, lane = tid & 63;
    const int wr = (wv >> 1) * 64;
    const int wc = (wv & 1) * 64;
    const int frow = lane & 15, fk = (lane >> 4) * 8, crow = (lane >> 4) * 4;

    const float* Wrow = attn_W + (size_t)(n0 + sr) * (2 * H) + kbase + sc;
    const u16* Abase = Ah + (size_t)sr * 4096 + kbase + sc;
    const u16* Lbase = Al + (size_t)sr * 4096 + kbase + sc;

    f32x4 acc[4][4];
    #pragma unroll
    for (int mi = 0; mi < 4; ++mi)
        #pragma unroll
        for (int ni = 0; ni < 4; ++ni)
            acc[mi][ni] = (f32x4){0.f, 0.f, 0.f, 0.f};

    u16x8 rah0, rah1, ral0, ral1;
    auto loadA = [&](int k0) {
        rah0 = *(const u16x8*)(Abase + k0);
        rah1 = *(const u16x8*)(Abase + k0 + 8);
        ral0 = *(const u16x8*)(Lbase + k0);
        ral1 = *(const u16x8*)(Lbase + k0 + 8);
    };
    auto writeA = [&]() {
        *(u16x8*)&AhS[sr][sc]     = rah0;
        *(u16x8*)&AhS[sr][sc + 8] = rah1;
        *(u16x8*)&AlS[sr][sc]     = ral0;
        *(u16x8*)&AlS[sr][sc + 8] = ral1;
    };
    f32x4 wX0, wX1, wX2, wX3, wY0, wY1, wY2, wY3;
    auto loadWX = [&](int k0) {
        wX0 = *(const f32x4*)(Wrow + k0);
        wX1 = *(const f32x4*)(Wrow + k0 + 4);
        wX2 = *(const f32x4*)(Wrow + k0 + 8);
        wX3 = *(const f32x4*)(Wrow + k0 + 12);
    };
    auto loadWY = [&](int k0) {
        wY0 = *(const f32x4*)(Wrow + k0);
        wY1 = *(const f32x4*)(Wrow + k0 + 4);
        wY2 = *(const f32x4*)(Wrow + k0 + 8);
        wY3 = *(const f32x4*)(Wrow + k0 + 12);
    };
    auto writeB = [&](const f32x4& b0, const f32x4& b1,
                      const f32x4& b2, const f32x4& b3) {
        u16x8 hv, lv;
        #pragma unroll
        for (int j = 0; j < 4; ++j) { u16 h, l; cvt_hilo(b0[j], h, l); hv[j] = h; lv[j] = l; }
        #pragma unroll
        for (int j = 0; j < 4; ++j) { u16 h, l; cvt_hilo(b1[j], h, l); hv[4+j] = h; lv[4+j] = l; }
        *(u16x8*)&BhS[sr][sc] = hv;
        *(u16x8*)&BlS[sr][sc] = lv;
        #pragma unroll
        for (int j = 0; j < 4; ++j) { u16 h, l; cvt_hilo(b2[j], h, l); hv[j] = h; lv[j] = l; }
        #pragma unroll
        for (int j = 0; j < 4; ++j) { u16 h, l; cvt_hilo(b3[j], h, l); hv[4+j] = h; lv[4+j] = l; }
        *(u16x8*)&BhS[sr][sc + 8] = hv;
        *(u16x8*)&BlS[sr][sc + 8] = lv;
    };
    auto computeTile = [&]() {
        bf16x8 a_h[4], a_l[4], b_h[4], b_l[4];
        #pragma unroll
        for (int mi = 0; mi < 4; ++mi) {
            a_h[mi] = *(const bf16x8*)&AhS[wr + mi * 16 + frow][fk];
            a_l[mi] = *(const bf16x8*)&AlS[wr + mi * 16 + frow][fk];
        }
        #pragma unroll
        for (int ni = 0; ni < 4; ++ni) {
            b_h[ni] = *(const bf16x8*)&BhS[wc + ni * 16 + frow][fk];
            b_l[ni] = *(const bf16x8*)&BlS[wc + ni * 16 + frow][fk];
        }
        #pragma unroll
        for (int mi = 0; mi < 4; ++mi)
            #pragma unroll
            for (int ni = 0; ni < 4; ++ni) {
                acc[mi][ni] = __builtin_amdgcn_mfma_f32_16x16x32_bf16(a_h[mi], b_h[ni], acc[mi][ni], 0, 0, 0);
                acc[mi][ni] = __builtin_amdgcn_mfma_f32_16x16x32_bf16(a_h[mi], b_l[ni], acc[mi][ni], 0, 0, 0);
                acc[mi][ni] = __builtin_amdgcn_mfma_f32_16x16x32_bf16(a_l[mi], b_h[ni], acc[mi][ni], 0, 0, 0);
            }
    };

    loadWX(0);
    loadWY(32);
    loadA(0);

    for (int ks = 0; ks < NITER; ks += 2) {
        __syncthreads();
        writeA();
        writeB(wX0, wX1, wX2, wX3);
        __syncthreads();
        loadA((ks + 1) * 32);
        if (ks + 2 < NITER) loadWX((ks + 2) * 32);
        computeTile();
        __syncthreads();
        writeA();
        writeB(wY0, wY1, wY2, wY3);
        __syncthreads();
        if (ks + 2 < NITER) loadA((ks + 2) * 32);
        if (ks + 3 < NITER) loadWY((ks + 3) * 32);
        computeTile();
    }

    #pragma unroll
    for (int mi = 0; mi < 4; ++mi)
        #pragma unroll
        for (int ni = 0; ni < 4; ++ni) {
            const int col = n0 + wc + ni * 16 + frow;
            #pragma unroll
            for (int j = 0; j < 4; ++j) {
                const int row = wr + mi * 16 + crow + j;
                outp[((size_t)kzout * B + row) * H + col] = acc[mi][ni][j];
            }
        }
}

// ---------------------------------------------------------------------------
// LSTM cell: sums 8 gate partials + biases, gates, writes hx_new f32 and
// its bf16 hi/lo into the GEMM-1 A buffer (cols 2048..4095).
// ---------------------------------------------------------------------------
__global__ __launch_bounds__(256) void lstm_cell(
    const float* __restrict__ gp,     // [8][128][8192]
    const float* __restrict__ cx,
    const float* __restrict__ b_ih,
    const float* __restrict__ b_hh,
    float* __restrict__ hxn,
    u16* __restrict__ Ah1, u16* __restrict__ Al1)
{
    const int t = blockIdx.x * 256 + threadIdx.x;   // 65536 threads
    const int b = t >> 9;
    const int h = (t & 511) * 4;
    const size_t PS = (size_t)B * FOURH;
    const float* g0 = gp + (size_t)b * FOURH;
    f32x4 gi = *(const f32x4*)(b_ih + h)       + *(const f32x4*)(b_hh + h);
    f32x4 gf = *(const f32x4*)(b_ih + H + h)   + *(const f32x4*)(b_hh + H + h);
    f32x4 gg = *(const f32x4*)(b_ih + 2*H + h) + *(const f32x4*)(b_hh + 2*H + h);
    f32x4 go = *(const f32x4*)(b_ih + 3*H + h) + *(const f32x4*)(b_hh + 3*H + h);
    #pragma unroll
    for (int p = 0; p < 8; ++p) {
        gi += *(const f32x4*)(g0 + p * PS + h);
        gf += *(const f32x4*)(g0 + p * PS + H + h);
        gg += *(const f32x4*)(g0 + p * PS + 2*H + h);
        go += *(const f32x4*)(g0 + p * PS + 3*H + h);
    }
    f32x4 cv = *(const f32x4*)(cx + (size_t)b * H + h);
    f32x4 hv;
    #pragma unroll
    for (int j = 0; j < 4; ++j) {
        float i_ = 1.f / (1.f + expf(-gi[j]));
        float f_ = 1.f / (1.f + expf(-gf[j]));
        float o_ = 1.f / (1.f + expf(-go[j]));
        float g_ = tanhf(gg[j]);
        float c_ = f_ * cv[j] + i_ * g_;
        hv[j] = o_ * tanhf(c_);
    }
    *(f32x4*)(hxn + (size_t)b * H + h) = hv;
    u16x4 hh, ll;
    #pragma unroll
    for (int j = 0; j < 4; ++j) { u16 a, l; cvt_hilo(hv[j], a, l); hh[j] = a; ll[j] = l; }
    *(u16x4*)(Ah1 + (size_t)b * 4096 + H + h) = hh;
    *(u16x4*)(Al1 + (size_t)b * 4096 + H + h) = ll;
}

// ---------------------------------------------------------------------------
// Merged kernel: blocks 0..511 = fused attention (flash-style, one pass over
// ew); blocks 512..639 = gemm1 hx-half (attn_W[:,2048:] @ hx_new), which
// depends only on lstm_cell and hides under attention's HBM stream.
// ---------------------------------------------------------------------------
__global__ __launch_bounds__(256) void fused_attn_g1(
    const float* __restrict__ hxn,     // [128][2048]
    const float* __restrict__ ew,      // [512][128][2048]
    const int* __restrict__ mask,      // [512][128]
    float* __restrict__ o_part,        // [128][4][2048] unnormalized
    float* __restrict__ ml_part,       // [128][4][2] = (M2, L) log2-domain
    const u16* __restrict__ Ah1, const u16* __restrict__ Al1,
    const float* __restrict__ attn_W,
    float* __restrict__ out_p)         // [16][128][2048]
{
    __shared__ __align__(16) unsigned char smem[41024];

    if (blockIdx.x >= 512) {
        const int bid = blockIdx.x - 512;
        const int n0 = (bid >> 3) * 128;
        const int kz = bid & 7;
        gemm1_tile(smem, Ah1, Al1, attn_W, n0, 2048 + kz * 256, 8 + kz, out_p);
        return;
    }

    float (*obuf)[2048] = (float(*)[2048])smem;            // 32 KB
    float (*mlbuf)[2]   = (float(*)[2])(smem + 32768);     // 32 B

    const int tid = threadIdx.x;
    const int b = blockIdx.x >> 2;
    const int c = blockIdx.x & 3;
    const int wv = tid >> 6;
    const int lane = tid & 63;
    const int s0 = c * 128 + wv * 32;

    unsigned long long mbits;
    {
        int mv = (lane < 32) ? mask[(s0 + lane) * B + b] : 0;
        mbits = __ballot(mv != 0);
    }

    f32x4 hxv[8];
    const float* hp = hxn + (size_t)b * H + lane * 4;
    #pragma unroll
    for (int j = 0; j < 8; ++j) hxv[j] = *(const f32x4*)(hp + j * 256);

    f32x4 o4[8];
    #pragma unroll
    for (int j = 0; j < 8; ++j) o4[j] = (f32x4){0.f, 0.f, 0.f, 0.f};
    float m2 = -3.0e38f, l = 0.f;

    const size_t SSTRIDE = (size_t)B * H;
    const float* rowp = ew + ((size_t)s0 * B + b) * H + lane * 4;

    f32x4 eva[8], evb[8];
    #pragma unroll
    for (int j = 0; j < 8; ++j) eva[j] = *(const f32x4*)(rowp + j * 256);
    #pragma unroll
    for (int j = 0; j < 8; ++j) evb[j] = *(const f32x4*)(rowp + SSTRIDE + j * 256);

    for (int pi = 0; pi < 16; ++pi) {
        f32x4 ca[8], cb[8];
        #pragma unroll
        for (int j = 0; j < 8; ++j) { ca[j] = eva[j]; cb[j] = evb[j]; }
        if (pi < 15) {
            const float* na = rowp + (size_t)(2 * pi + 2) * SSTRIDE;
            const float* nb = rowp + (size_t)(2 * pi + 3) * SSTRIDE;
            #pragma unroll
            for (int j = 0; j < 8; ++j) eva[j] = *(const f32x4*)(na + j * 256);
            #pragma unroll
            for (int j = 0; j < 8; ++j) evb[j] = *(const f32x4*)(nb + j * 256);
        }
        float pa = 0.f, pb = 0.f;
        #pragma unroll
        for (int j = 0; j < 8; ++j) {
            f32x4 ta = ca[j] * hxv[j];
            f32x4 tb = cb[j] * hxv[j];
            pa += ta[0] + ta[1] + ta[2] + ta[3];
            pb += tb[0] + tb[1] + tb[2] + tb[3];
        }
        #pragma unroll
        for (int off = 32; off; off >>= 1) {
            pa += __shfl_xor(pa, off, 64);
            pb += __shfl_xor(pb, off, 64);
        }
        const float p2a = ((mbits >> (2 * pi)) & 1) ? pa * LOG2E : -1.5e9f;
        const float p2b = ((mbits >> (2 * pi + 1)) & 1) ? pb * LOG2E : -1.5e9f;
        const float q = fmaxf(p2a, p2b);
        if (q <= m2) {
            const float ea = exp2f(p2a - m2);
            const float eb = exp2f(p2b - m2);
            l += ea + eb;
            #pragma unroll
            for (int j = 0; j < 8; ++j) o4[j] += ca[j] * ea + cb[j] * eb;
        } else {
            const float sc = exp2f(m2 - q);
            const float ea = exp2f(p2a - q);
            const float eb = exp2f(p2b - q);
            l = l * sc + ea + eb;
            #pragma unroll
            for (int j = 0; j < 8; ++j) o4[j] = o4[j] * sc + ca[j] * ea + cb[j] * eb;
            m2 = q;
        }
    }

    if (lane == 0) { mlbuf[wv][0] = m2; mlbuf[wv][1] = l; }
    __syncthreads();
    const float M = fmaxf(fmaxf(mlbuf[0][0], mlbuf[1][0]), fmaxf(mlbuf[2][0], mlbuf[3][0]));
    const float wsc = exp2f(m2 - M);
    float L = 0.f;
    #pragma unroll
    for (int w = 0; w < 4; ++w) L += mlbuf[w][1] * exp2f(mlbuf[w][0] - M);
    #pragma unroll
    for (int j = 0; j < 8; ++j)
        *(f32x4*)&obuf[wv][j * 256 + lane * 4] = o4[j] * wsc;
    __syncthreads();

    const int h0 = tid * 8;
    f32x4 s0v = (f32x4){0.f, 0.f, 0.f, 0.f}, s1v = s0v;
    #pragma unroll
    for (int w = 0; w < 4; ++w) {
        s0v += *(const f32x4*)&obuf[w][h0];
        s1v += *(const f32x4*)&obuf[w][h0 + 4];
    }
    float* op = o_part + ((size_t)b * 4 + c) * H + h0;
    *(f32x4*)(op)     = s0v;
    *(f32x4*)(op + 4) = s1v;
    if (tid == 0) {
        ml_part[((size_t)b * 4 + c) * 2]     = M;
        ml_part[((size_t)b * 4 + c) * 2 + 1] = L;
    }
}

// ---------------------------------------------------------------------------
// Combine 4 chunk-partials -> content, written as bf16 hi/lo into A1[:,0:2048]
// ---------------------------------------------------------------------------
__global__ __launch_bounds__(256) void attn_combine(
    const float* __restrict__ o_part,
    const float* __restrict__ ml_part,
    u16* __restrict__ Ah1, u16* __restrict__ Al1)
{
    const int b = blockIdx.x;
    const int tid = threadIdx.x;
    float Mc[4], Lc[4];
    #pragma unroll
    for (int c = 0; c < 4; ++c) {
        Mc[c] = ml_part[((size_t)b * 4 + c) * 2];
        Lc[c] = ml_part[((size_t)b * 4 + c) * 2 + 1];
    }
    const float Mg = fmaxf(fmaxf(Mc[0], Mc[1]), fmaxf(Mc[2], Mc[3]));
    float Lg = 0.f;
    #pragma unroll
    for (int c = 0; c < 4; ++c) Lg += Lc[c] * exp2f(Mc[c] - Mg);
    const float inv = 1.f / Lg;
    const int h0 = tid * 8;
    f32x4 a0 = (f32x4){0.f, 0.f, 0.f, 0.f}, a1 = a0;
    #pragma unroll
    for (int c = 0; c < 4; ++c) {
        const float scl = exp2f(Mc[c] - Mg) * inv;
        const float* op = o_part + ((size_t)b * 4 + c) * H + h0;
        a0 += *(const f32x4*)(op) * scl;
        a1 += *(const f32x4*)(op + 4) * scl;
    }
    u16x8 hh, ll;
    #pragma unroll
    for (int j = 0; j < 4; ++j) { u16 a, l; cvt_hilo(a0[j], a, l); hh[j] = a; ll[j] = l; }
    #pragma unroll
    for (int j = 0; j < 4; ++j) { u16 a, l; cvt_hilo(a1[j], a, l); hh[4+j] = a; ll[4+j] = l; }
    *(u16x8*)(Ah1 + (size_t)b * 4096 + h0) = hh;
    *(u16x8*)(Al1 + (size_t)b * 4096 + h0) = ll;
}

// ---------------------------------------------------------------------------
// gemm1 content half: out_p[kz] = A1[:,0:2048-slice] @ attn_W[:, :2048]^T
// grid (16 n-tiles x 8 kz) = 128 blocks.
// ---------------------------------------------------------------------------
__global__ __launch_bounds__(256) void gemm1_content(
    const u16* __restrict__ Ah1, const u16* __restrict__ Al1,
    const float* __restrict__ attn_W,
    float* __restrict__ out_p)
{
    __shared__ __align__(16) unsigned char smem[41024];
    const int n0 = (blockIdx.x >> 3) * 128;
    const int kz = blockIdx.x & 7;
    gemm1_tile(smem, Ah1, Al1, attn_W, n0, kz * 256, kz, out_p);
}

// ---------------------------------------------------------------------------
// Output epilogue: out = tanh(sum of 16 K-partials + attn_b)
// ---------------------------------------------------------------------------
__global__ __launch_bounds__(256) void attn_out(
    const float* __restrict__ part,    // [16][128][2048]
    const float* __restrict__ attn_b,
    float* __restrict__ out)
{
    const int t = blockIdx.x * 256 + threadIdx.x;   // 65536 threads
    const int i = t * 4;
    const int n = i & (H - 1);
    const size_t BH = (size_t)B * H;
    f32x4 s = *(const f32x4*)(attn_b + n);
    #pragma unroll
    for (int p = 0; p < 16; ++p) s += *(const f32x4*)(part + p * BH + i);
    f32x4 r;
    #pragma unroll
    for (int j = 0; j < 4; ++j) r[j] = tanhf(s[j]);
    *(f32x4*)(out + i) = r;
}

// ---------------------------------------------------------------------------
extern "C" void kernel_launch(void* const* d_in, const int* in_sizes, int n_in,
                              void* d_out, int out_size, void* d_ws, size_t ws_size,
                              hipStream_t stream)
{
    const int*   tw     = (const int*)d_in[0];
    const float* hx     = (const float*)d_in[1];
    const float* cx     = (const float*)d_in[2];
    const float* ew     = (const float*)d_in[3];
    const int*   mask   = (const int*)d_in[4];
    const float* embed  = (const float*)d_in[5];
    const float* W_ih   = (const float*)d_in[6];
    const float* W_hh   = (const float*)d_in[7];
    const float* b_ih   = (const float*)d_in[8];
    const float* b_hh   = (const float*)d_in[9];
    const float* attn_W = (const float*)d_in[10];
    const float* attn_b = (const float*)d_in[11];
    float* out = (float*)d_out;

    float* ws      = (float*)d_ws;
    float* gates_p = ws;                                  // 8*128*8192
    float* o_part  = gates_p + 8 * (size_t)B * FOURH;     // 128*4*2048
    float* ml      = o_part + (size_t)B * 4 * H;          // 1024
    float* hxn     = ml + 1024;                           // 128*2048
    float* out_p   = hxn + (size_t)B * H;                 // 16*128*2048
    u16* Ah0 = (u16*)(out_p + 16 * (size_t)B * H);
    u16* Al0 = Ah0 + (size_t)B * 4096;
    u16* Ah1 = Al0 + (size_t)B * 4096;
    u16* Al1 = Ah1 + (size_t)B * 4096;

    gather_convert_A0<<<256, 256, 0, stream>>>(tw, embed, hx, Ah0, Al0);
    gates_gemm<<<dim3(FOURH / 128, 8), 256, 0, stream>>>(Ah0, Al0, W_ih, W_hh, gates_p);
    lstm_cell<<<256, 256, 0, stream>>>(gates_p, cx, b_ih, b_hh, hxn, Ah1, Al1);
    fused_attn_g1<<<512 + 128, 256, 0, stream>>>(hxn, ew, mask, o_part, ml,
                                                 Ah1, Al1, attn_W, out_p);
    attn_combine<<<B, 256, 0, stream>>>(o_part, ml, Ah1, Al1);
    gemm1_content<<<128, 256, 0, stream>>>(Ah1, Al1, attn_W, out_p);
    attn_out<<<256, 256, 0, stream>>>(out_p, attn_b, out);
}

// Round 8
// 186.163 us; speedup vs baseline: 1.0212x; 1.0212x over previous
//
#include <hip/hip_runtime.h>
#include <math.h>

#define B 128
#define H 2048
#define S 512
#define FOURH 8192
#define LOG2E 1.4426950408889634f

typedef float  f32x4  __attribute__((ext_vector_type(4)));
typedef short  bf16x8 __attribute__((ext_vector_type(8)));
typedef unsigned short u16;
typedef unsigned short u16x8 __attribute__((ext_vector_type(8)));
typedef unsigned short u16x4 __attribute__((ext_vector_type(4)));

// Split f32 -> bf16 hi + bf16 lo (truncation; lo captures residual, total ~2^-16)
__device__ __forceinline__ void cvt_hilo(float x, u16& h, u16& lo) {
    unsigned int u = __float_as_uint(x);
    h = (u16)(u >> 16);
    float hf = __uint_as_float(u & 0xFFFF0000u);
    float r = x - hf;
    lo = (u16)(__float_as_uint(r) >> 16);
}

// ---------------------------------------------------------------------------
// Kernel 1: build A0 = [embed[tw] | hx] as bf16 hi/lo pair [128][4096]
// ---------------------------------------------------------------------------
__global__ __launch_bounds__(256) void gather_convert_A0(
    const int* __restrict__ tw,
    const float* __restrict__ embed,
    const float* __restrict__ hx,
    u16* __restrict__ Ah, u16* __restrict__ Al)
{
    const int i = (blockIdx.x * 256 + threadIdx.x) * 8;   // over 128*4096
    const int b = i >> 12;
    const int col = i & 4095;
    const float* src = (col < H) ? (embed + (size_t)tw[b] * H + col)
                                 : (hx + (size_t)b * H + (col - H));
    f32x4 v0 = *(const f32x4*)(src);
    f32x4 v1 = *(const f32x4*)(src + 4);
    u16x8 hv, lv;
    #pragma unroll
    for (int j = 0; j < 4; ++j) { u16 h, l; cvt_hilo(v0[j], h, l); hv[j] = h; lv[j] = l; }
    #pragma unroll
    for (int j = 0; j < 4; ++j) { u16 h, l; cvt_hilo(v1[j], h, l); hv[4+j] = h; lv[4+j] = l; }
    *(u16x8*)(Ah + i) = hv;
    *(u16x8*)(Al + i) = lv;
}

// ---------------------------------------------------------------------------
// Split-bf16 MFMA GEMM, 128x128 tile, split-K partials.
// BM=128, BN=128, BK=32, 256 threads = 4 waves in a 2x2 grid; each wave owns
// a 64x64 sub-tile = 4x4 fragments -> 48 MFMA per K-iter per wave against
// 16 ds_read_b128 (3:1).
// 3 MFMA per frag pair: Ah*Wh + Ah*Wl + Al*Wh (err ~2^-16).
// MODE 0: K=4096 split 8 (kz<4 -> W_ih, else W_hh; offset (kz&3)*512);
//         grid (64,8), out [8][128][8192]
// MODE 1: K=4096 split 16 over attn_W [2048][4096]; grid (16,16),
//         out [16][128][2048]
// W prefetch 2-deep (sets X/Y); A prefetch 1-deep (L2-resident).
// ---------------------------------------------------------------------------
template<int MODE>
__global__ __launch_bounds__(256) void split_gemm(
    const u16* __restrict__ Ah, const u16* __restrict__ Al,
    const float* __restrict__ W0, const float* __restrict__ W1,
    float* __restrict__ outp)
{
    constexpr int NOUT = (MODE == 0) ? FOURH : H;
    constexpr int KLEN = (MODE == 0) ? 512 : 256;
    constexpr int NITER = KLEN / 32;       // 16 or 8 (even)
    __shared__ u16 AhS[128][40];
    __shared__ u16 AlS[128][40];
    __shared__ u16 BhS[128][40];
    __shared__ u16 BlS[128][40];

    const int tid = threadIdx.x;
    const int n0 = blockIdx.x * 128;
    const int kz = blockIdx.y;
    const int kbase = kz * KLEN;
    // staging coords: thread -> (row 0..127, 16-col half)
    const int sr = tid >> 1;
    const int sc = (tid & 1) * 16;
    // wave/frag coords
    const int wv = tid >> 6, lane = tid & 63;
    const int wr = (wv >> 1) * 64;         // wave row base
    const int wc = (wv & 1) * 64;          // wave col base
    const int frow = lane & 15, fk = (lane >> 4) * 8, crow = (lane >> 4) * 4;

    const float* Wrow;
    if (MODE == 0)
        Wrow = ((kz < 4) ? W0 : W1) + (size_t)(n0 + sr) * H + (kz & 3) * KLEN + sc;
    else
        Wrow = W0 + (size_t)(n0 + sr) * (2 * H) + kbase + sc;

    const u16* Abase = Ah + (size_t)sr * 4096 + kbase + sc;
    const u16* Lbase = Al + (size_t)sr * 4096 + kbase + sc;

    f32x4 acc[4][4];
    #pragma unroll
    for (int mi = 0; mi < 4; ++mi)
        #pragma unroll
        for (int ni = 0; ni < 4; ++ni)
            acc[mi][ni] = (f32x4){0.f, 0.f, 0.f, 0.f};

    u16x8 rah0, rah1, ral0, ral1;
    auto loadA = [&](int k0) {
        rah0 = *(const u16x8*)(Abase + k0);
        rah1 = *(const u16x8*)(Abase + k0 + 8);
        ral0 = *(const u16x8*)(Lbase + k0);
        ral1 = *(const u16x8*)(Lbase + k0 + 8);
    };
    auto writeA = [&]() {
        *(u16x8*)&AhS[sr][sc]     = rah0;
        *(u16x8*)&AhS[sr][sc + 8] = rah1;
        *(u16x8*)&AlS[sr][sc]     = ral0;
        *(u16x8*)&AlS[sr][sc + 8] = ral1;
    };
    // two named W prefetch sets (rule #20: static names, no runtime indexing)
    f32x4 wX0, wX1, wX2, wX3, wY0, wY1, wY2, wY3;
    auto loadWX = [&](int k0) {
        wX0 = *(const f32x4*)(Wrow + k0);
        wX1 = *(const f32x4*)(Wrow + k0 + 4);
        wX2 = *(const f32x4*)(Wrow + k0 + 8);
        wX3 = *(const f32x4*)(Wrow + k0 + 12);
    };
    auto loadWY = [&](int k0) {
        wY0 = *(const f32x4*)(Wrow + k0);
        wY1 = *(const f32x4*)(Wrow + k0 + 4);
        wY2 = *(const f32x4*)(Wrow + k0 + 8);
        wY3 = *(const f32x4*)(Wrow + k0 + 12);
    };
    auto writeB = [&](const f32x4& b0, const f32x4& b1,
                      const f32x4& b2, const f32x4& b3) {
        u16x8 hv, lv;
        #pragma unroll
        for (int j = 0; j < 4; ++j) { u16 h, l; cvt_hilo(b0[j], h, l); hv[j] = h; lv[j] = l; }
        #pragma unroll
        for (int j = 0; j < 4; ++j) { u16 h, l; cvt_hilo(b1[j], h, l); hv[4+j] = h; lv[4+j] = l; }
        *(u16x8*)&BhS[sr][sc] = hv;
        *(u16x8*)&BlS[sr][sc] = lv;
        #pragma unroll
        for (int j = 0; j < 4; ++j) { u16 h, l; cvt_hilo(b2[j], h, l); hv[j] = h; lv[j] = l; }
        #pragma unroll
        for (int j = 0; j < 4; ++j) { u16 h, l; cvt_hilo(b3[j], h, l); hv[4+j] = h; lv[4+j] = l; }
        *(u16x8*)&BhS[sr][sc + 8] = hv;
        *(u16x8*)&BlS[sr][sc + 8] = lv;
    };
    auto computeTile = [&]() {
        bf16x8 a_h[4], a_l[4], b_h[4], b_l[4];
        #pragma unroll
        for (int mi = 0; mi < 4; ++mi) {
            a_h[mi] = *(const bf16x8*)&AhS[wr + mi * 16 + frow][fk];
            a_l[mi] = *(const bf16x8*)&AlS[wr + mi * 16 + frow][fk];
        }
        #pragma unroll
        for (int ni = 0; ni < 4; ++ni) {
            b_h[ni] = *(const bf16x8*)&BhS[wc + ni * 16 + frow][fk];
            b_l[ni] = *(const bf16x8*)&BlS[wc + ni * 16 + frow][fk];
        }
        #pragma unroll
        for (int mi = 0; mi < 4; ++mi)
            #pragma unroll
            for (int ni = 0; ni < 4; ++ni) {
                acc[mi][ni] = __builtin_amdgcn_mfma_f32_16x16x32_bf16(a_h[mi], b_h[ni], acc[mi][ni], 0, 0, 0);
                acc[mi][ni] = __builtin_amdgcn_mfma_f32_16x16x32_bf16(a_h[mi], b_l[ni], acc[mi][ni], 0, 0, 0);
                acc[mi][ni] = __builtin_amdgcn_mfma_f32_16x16x32_bf16(a_l[mi], b_h[ni], acc[mi][ni], 0, 0, 0);
            }
    };

    loadWX(0);
    loadWY(32);
    loadA(0);

    for (int ks = 0; ks < NITER; ks += 2) {
        // half 1: tile ks (A regs + W set X)
        __syncthreads();
        writeA();
        writeB(wX0, wX1, wX2, wX3);
        __syncthreads();
        loadA((ks + 1) * 32);                     // NITER even: always valid
        if (ks + 2 < NITER) loadWX((ks + 2) * 32);
        computeTile();
        // half 2: tile ks+1 (A regs + W set Y)
        __syncthreads();
        writeA();
        writeB(wY0, wY1, wY2, wY3);
        __syncthreads();
        if (ks + 2 < NITER) loadA((ks + 2) * 32);
        if (ks + 3 < NITER) loadWY((ks + 3) * 32);
        computeTile();
    }

    // C/D layout: col=lane&15, row=(lane>>4)*4+j  [m89/m91]
    #pragma unroll
    for (int mi = 0; mi < 4; ++mi)
        #pragma unroll
        for (int ni = 0; ni < 4; ++ni) {
            const int col = n0 + wc + ni * 16 + frow;
            #pragma unroll
            for (int j = 0; j < 4; ++j) {
                const int row = wr + mi * 16 + crow + j;
                outp[((size_t)kz * B + row) * NOUT + col] = acc[mi][ni][j];
            }
        }
}

// ---------------------------------------------------------------------------
// LSTM cell: sums 8 gate partials + biases, gates, writes hx_new f32 and
// its bf16 hi/lo into the GEMM-1 A buffer (cols 2048..4095).
// ---------------------------------------------------------------------------
__global__ __launch_bounds__(256) void lstm_cell(
    const float* __restrict__ gp,     // [8][128][8192]
    const float* __restrict__ cx,
    const float* __restrict__ b_ih,
    const float* __restrict__ b_hh,
    float* __restrict__ hxn,
    u16* __restrict__ Ah1, u16* __restrict__ Al1)
{
    const int t = blockIdx.x * 256 + threadIdx.x;   // 65536 threads
    const int b = t >> 9;
    const int h = (t & 511) * 4;
    const size_t PS = (size_t)B * FOURH;
    const float* g0 = gp + (size_t)b * FOURH;
    f32x4 gi = *(const f32x4*)(b_ih + h)       + *(const f32x4*)(b_hh + h);
    f32x4 gf = *(const f32x4*)(b_ih + H + h)   + *(const f32x4*)(b_hh + H + h);
    f32x4 gg = *(const f32x4*)(b_ih + 2*H + h) + *(const f32x4*)(b_hh + 2*H + h);
    f32x4 go = *(const f32x4*)(b_ih + 3*H + h) + *(const f32x4*)(b_hh + 3*H + h);
    #pragma unroll
    for (int p = 0; p < 8; ++p) {
        gi += *(const f32x4*)(g0 + p * PS + h);
        gf += *(const f32x4*)(g0 + p * PS + H + h);
        gg += *(const f32x4*)(g0 + p * PS + 2*H + h);
        go += *(const f32x4*)(g0 + p * PS + 3*H + h);
    }
    f32x4 cv = *(const f32x4*)(cx + (size_t)b * H + h);
    f32x4 hv;
    #pragma unroll
    for (int j = 0; j < 4; ++j) {
        float i_ = 1.f / (1.f + expf(-gi[j]));
        float f_ = 1.f / (1.f + expf(-gf[j]));
        float o_ = 1.f / (1.f + expf(-go[j]));
        float g_ = tanhf(gg[j]);
        float c_ = f_ * cv[j] + i_ * g_;
        hv[j] = o_ * tanhf(c_);
    }
    *(f32x4*)(hxn + (size_t)b * H + h) = hv;
    u16x4 hh, ll;
    #pragma unroll
    for (int j = 0; j < 4; ++j) { u16 a, l; cvt_hilo(hv[j], a, l); hh[j] = a; ll[j] = l; }
    *(u16x4*)(Ah1 + (size_t)b * 4096 + H + h) = hh;
    *(u16x4*)(Al1 + (size_t)b * 4096 + H + h) = ll;
}

// ---------------------------------------------------------------------------
// Fused attention: one pass over ew, online softmax in log2 domain.
// Grid: 512 blocks = 128 b x 4 chunks of 128 s. Wave w owns 32 s, processed
// in PAIRS (2 rows/iter): 16 KB in flight, 2 independent dots per softmax
// update. Defer-rescale on the pair max.
// ---------------------------------------------------------------------------
__global__ __launch_bounds__(256) void fused_attn(
    const float* __restrict__ hxn,     // [128][2048]
    const float* __restrict__ ew,      // [512][128][2048]
    const int* __restrict__ mask,      // [512][128]
    float* __restrict__ o_part,        // [128][4][2048] unnormalized
    float* __restrict__ ml_part)       // [128][4][2] = (M2, L) log2-domain
{
    __shared__ float mlbuf[4][2];
    __shared__ float obuf[4][2048];

    const int tid = threadIdx.x;
    const int b = blockIdx.x >> 2;
    const int c = blockIdx.x & 3;
    const int wv = tid >> 6;
    const int lane = tid & 63;
    const int s0 = c * 128 + wv * 32;

    // mask bits for this wave's 32 s-values
    unsigned long long mbits;
    {
        int mv = (lane < 32) ? mask[(s0 + lane) * B + b] : 0;
        mbits = __ballot(mv != 0);
    }

    f32x4 hxv[8];
    const float* hp = hxn + (size_t)b * H + lane * 4;
    #pragma unroll
    for (int j = 0; j < 8; ++j) hxv[j] = *(const f32x4*)(hp + j * 256);

    f32x4 o4[8];
    #pragma unroll
    for (int j = 0; j < 8; ++j) o4[j] = (f32x4){0.f, 0.f, 0.f, 0.f};
    float m2 = -3.0e38f, l = 0.f;

    const size_t SSTRIDE = (size_t)B * H;
    const float* rowp = ew + ((size_t)s0 * B + b) * H + lane * 4;

    f32x4 eva[8], evb[8];
    #pragma unroll
    for (int j = 0; j < 8; ++j) eva[j] = *(const f32x4*)(rowp + j * 256);
    #pragma unroll
    for (int j = 0; j < 8; ++j) evb[j] = *(const f32x4*)(rowp + SSTRIDE + j * 256);

    for (int pi = 0; pi < 16; ++pi) {
        f32x4 ca[8], cb[8];
        #pragma unroll
        for (int j = 0; j < 8; ++j) { ca[j] = eva[j]; cb[j] = evb[j]; }
        if (pi < 15) {
            const float* na = rowp + (size_t)(2 * pi + 2) * SSTRIDE;
            const float* nb = rowp + (size_t)(2 * pi + 3) * SSTRIDE;
            #pragma unroll
            for (int j = 0; j < 8; ++j) eva[j] = *(const f32x4*)(na + j * 256);
            #pragma unroll
            for (int j = 0; j < 8; ++j) evb[j] = *(const f32x4*)(nb + j * 256);
        }
        float pa = 0.f, pb = 0.f;
        #pragma unroll
        for (int j = 0; j < 8; ++j) {
            f32x4 ta = ca[j] * hxv[j];
            f32x4 tb = cb[j] * hxv[j];
            pa += ta[0] + ta[1] + ta[2] + ta[3];
            pb += tb[0] + tb[1] + tb[2] + tb[3];
        }
        #pragma unroll
        for (int off = 32; off; off >>= 1) {
            pa += __shfl_xor(pa, off, 64);
            pb += __shfl_xor(pb, off, 64);
        }
        const float p2a = ((mbits >> (2 * pi)) & 1) ? pa * LOG2E : -1.5e9f;
        const float p2b = ((mbits >> (2 * pi + 1)) & 1) ? pb * LOG2E : -1.5e9f;
        const float q = fmaxf(p2a, p2b);
        if (q <= m2) {
            // common path: no new max, no o4 rescale
            const float ea = exp2f(p2a - m2);
            const float eb = exp2f(p2b - m2);
            l += ea + eb;
            #pragma unroll
            for (int j = 0; j < 8; ++j) o4[j] += ca[j] * ea + cb[j] * eb;
        } else {
            const float sc = exp2f(m2 - q);
            const float ea = exp2f(p2a - q);
            const float eb = exp2f(p2b - q);
            l = l * sc + ea + eb;
            #pragma unroll
            for (int j = 0; j < 8; ++j) o4[j] = o4[j] * sc + ca[j] * ea + cb[j] * eb;
            m2 = q;
        }
    }

    if (lane == 0) { mlbuf[wv][0] = m2; mlbuf[wv][1] = l; }
    __syncthreads();
    const float M = fmaxf(fmaxf(mlbuf[0][0], mlbuf[1][0]), fmaxf(mlbuf[2][0], mlbuf[3][0]));
    const float wsc = exp2f(m2 - M);
    float L = 0.f;
    #pragma unroll
    for (int w = 0; w < 4; ++w) L += mlbuf[w][1] * exp2f(mlbuf[w][0] - M);
    #pragma unroll
    for (int j = 0; j < 8; ++j)
        *(f32x4*)&obuf[wv][j * 256 + lane * 4] = o4[j] * wsc;
    __syncthreads();

    const int h0 = tid * 8;
    f32x4 s0v = (f32x4){0.f, 0.f, 0.f, 0.f}, s1v = s0v;
    #pragma unroll
    for (int w = 0; w < 4; ++w) {
        s0v += *(const f32x4*)&obuf[w][h0];
        s1v += *(const f32x4*)&obuf[w][h0 + 4];
    }
    float* op = o_part + ((size_t)b * 4 + c) * H + h0;
    *(f32x4*)(op)     = s0v;
    *(f32x4*)(op + 4) = s1v;
    if (tid == 0) {
        ml_part[((size_t)b * 4 + c) * 2]     = M;
        ml_part[((size_t)b * 4 + c) * 2 + 1] = L;
    }
}

// ---------------------------------------------------------------------------
// Combine 4 chunk-partials -> content, written as bf16 hi/lo into A1[:,0:2048]
// ---------------------------------------------------------------------------
__global__ __launch_bounds__(256) void attn_combine(
    const float* __restrict__ o_part,
    const float* __restrict__ ml_part,
    u16* __restrict__ Ah1, u16* __restrict__ Al1)
{
    const int b = blockIdx.x;
    const int tid = threadIdx.x;
    float Mc[4], Lc[4];
    #pragma unroll
    for (int c = 0; c < 4; ++c) {
        Mc[c] = ml_part[((size_t)b * 4 + c) * 2];
        Lc[c] = ml_part[((size_t)b * 4 + c) * 2 + 1];
    }
    const float Mg = fmaxf(fmaxf(Mc[0], Mc[1]), fmaxf(Mc[2], Mc[3]));
    float Lg = 0.f;
    #pragma unroll
    for (int c = 0; c < 4; ++c) Lg += Lc[c] * exp2f(Mc[c] - Mg);
    const float inv = 1.f / Lg;
    const int h0 = tid * 8;
    f32x4 a0 = (f32x4){0.f, 0.f, 0.f, 0.f}, a1 = a0;
    #pragma unroll
    for (int c = 0; c < 4; ++c) {
        const float scl = exp2f(Mc[c] - Mg) * inv;
        const float* op = o_part + ((size_t)b * 4 + c) * H + h0;
        a0 += *(const f32x4*)(op) * scl;
        a1 += *(const f32x4*)(op + 4) * scl;
    }
    u16x8 hh, ll;
    #pragma unroll
    for (int j = 0; j < 4; ++j) { u16 a, l; cvt_hilo(a0[j], a, l); hh[j] = a; ll[j] = l; }
    #pragma unroll
    for (int j = 0; j < 4; ++j) { u16 a, l; cvt_hilo(a1[j], a, l); hh[4+j] = a; ll[4+j] = l; }
    *(u16x8*)(Ah1 + (size_t)b * 4096 + h0) = hh;
    *(u16x8*)(Al1 + (size_t)b * 4096 + h0) = ll;
}

// ---------------------------------------------------------------------------
// Output epilogue: out = tanh(sum of 16 K-partials + attn_b)
// ---------------------------------------------------------------------------
__global__ __launch_bounds__(256) void attn_out(
    const float* __restrict__ part,    // [16][128][2048]
    const float* __restrict__ attn_b,
    float* __restrict__ out)
{
    const int t = blockIdx.x * 256 + threadIdx.x;   // 65536 threads
    const int i = t * 4;
    const int n = i & (H - 1);
    const size_t BH = (size_t)B * H;
    f32x4 s = *(const f32x4*)(attn_b + n);
    #pragma unroll
    for (int p = 0; p < 16; ++p) s += *(const f32x4*)(part + p * BH + i);
    f32x4 r;
    #pragma unroll
    for (int j = 0; j < 4; ++j) r[j] = tanhf(s[j]);
    *(f32x4*)(out + i) = r;
}

// ---------------------------------------------------------------------------
extern "C" void kernel_launch(void* const* d_in, const int* in_sizes, int n_in,
                              void* d_out, int out_size, void* d_ws, size_t ws_size,
                              hipStream_t stream)
{
    const int*   tw     = (const int*)d_in[0];
    const float* hx     = (const float*)d_in[1];
    const float* cx     = (const float*)d_in[2];
    const float* ew     = (const float*)d_in[3];
    const int*   mask   = (const int*)d_in[4];
    const float* embed  = (const float*)d_in[5];
    const float* W_ih   = (const float*)d_in[6];
    const float* W_hh   = (const float*)d_in[7];
    const float* b_ih   = (const float*)d_in[8];
    const float* b_hh   = (const float*)d_in[9];
    const float* attn_W = (const float*)d_in[10];
    const float* attn_b = (const float*)d_in[11];
    float* out = (float*)d_out;

    float* ws      = (float*)d_ws;
    float* gates_p = ws;                                  // 8*128*8192
    float* o_part  = gates_p + 8 * (size_t)B * FOURH;     // 128*4*2048
    float* ml      = o_part + (size_t)B * 4 * H;          // 1024
    float* hxn     = ml + 1024;                           // 128*2048
    float* out_p   = hxn + (size_t)B * H;                 // 16*128*2048
    u16* Ah0 = (u16*)(out_p + 16 * (size_t)B * H);
    u16* Al0 = Ah0 + (size_t)B * 4096;
    u16* Ah1 = Al0 + (size_t)B * 4096;
    u16* Al1 = Ah1 + (size_t)B * 4096;

    gather_convert_A0<<<256, 256, 0, stream>>>(tw, embed, hx, Ah0, Al0);
    split_gemm<0><<<dim3(FOURH / 128, 8), 256, 0, stream>>>(Ah0, Al0, W_ih, W_hh, gates_p);
    lstm_cell<<<256, 256, 0, stream>>>(gates_p, cx, b_ih, b_hh, hxn, Ah1, Al1);
    fused_attn<<<B * 4, 256, 0, stream>>>(hxn, ew, mask, o_part, ml);
    attn_combine<<<B, 256, 0, stream>>>(o_part, ml, Ah1, Al1);
    split_gemm<1><<<dim3(H / 128, 16), 256, 0, stream>>>(Ah1, Al1, attn_W, attn_W, out_p);
    attn_out<<<256, 256, 0, stream>>>(out_p, attn_b, out);
}